// Round 7
// baseline (373.114 us; speedup 1.0000x reference)
//
#include <hip/hip_runtime.h>

// Problem constants: B=4, S=2048, D=1024, H=16, DK=64
#define BB 4
#define SS 2048
#define DD 1024
#define HH 16
#define DKK 64
#define MTOT (BB * SS)          // 8192
#define QKV_N (MTOT * DD)       // 8388608 = 2^23
#define W_N (DD * DD)           // 1048576

typedef __attribute__((ext_vector_type(8))) short short8;     // 8 bf16 (MFMA A/B frag)
typedef __attribute__((ext_vector_type(4))) float f32x4;      // MFMA C/D frag
typedef __attribute__((ext_vector_type(4))) unsigned short u16x4;
typedef unsigned short ushort_t;

#define GP(p) ((__attribute__((address_space(1))) void*)(p))
#define LP(p) ((__attribute__((address_space(3))) void*)(p))

// exp2-domain softmax: Q pre-scaled by log2(e)/8 so p = 2^(s-m) via v_exp_f32
#if __has_builtin(__builtin_amdgcn_exp2f)
#define EXP2(x) __builtin_amdgcn_exp2f(x)
#else
#define EXP2(x) __expf((x) * 0.6931471805599453f)
#endif
#define QSCALE 0.1803368801111204f   // (1/8) * log2(e)

__device__ __forceinline__ ushort_t f2bf(float f) {
    union { float f; unsigned u; } c; c.f = f;
    unsigned r = c.u + 0x7fffu + ((c.u >> 16) & 1u);   // RNE; inputs finite
    return (ushort_t)(r >> 16);
}

__device__ __forceinline__ short8 pack8(f32x4 lo, f32x4 hi) {
    short8 r;
    r[0] = (short)f2bf(lo[0]); r[1] = (short)f2bf(lo[1]);
    r[2] = (short)f2bf(lo[2]); r[3] = (short)f2bf(lo[3]);
    r[4] = (short)f2bf(hi[0]); r[5] = (short)f2bf(hi[1]);
    r[6] = (short)f2bf(hi[2]); r[7] = (short)f2bf(hi[3]);
    return r;
}

// ---------------------------------------------------------------------------
// fp32 -> bf16 convert for q,k,v in one dispatch (QKV_N = 2^23 each)
// ---------------------------------------------------------------------------
__global__ __launch_bounds__(256)
void cvt3(const float* __restrict__ q, const float* __restrict__ k,
          const float* __restrict__ v, ushort_t* __restrict__ qb,
          ushort_t* __restrict__ kb, ushort_t* __restrict__ vb)
{
    size_t i = ((size_t)blockIdx.x * 256 + threadIdx.x) * 4;
    int seg = (int)(i >> 23);
    size_t off = i & (size_t)(QKV_N - 1);
    const float* s = (seg == 0) ? q : (seg == 1) ? k : v;
    ushort_t*    d = (seg == 0) ? qb : (seg == 1) ? kb : vb;
    f32x4 x = *(const f32x4*)(s + off);
    u16x4 h;
    h[0] = f2bf(x[0]); h[1] = f2bf(x[1]); h[2] = f2bf(x[2]); h[3] = f2bf(x[3]);
    *(u16x4*)(d + off) = h;
}

// ===========================================================================
// Shared GEMM K-loop machinery: C[128,128] tile = A[M,K]bf16 * W[N,K]^T fp32.
// BK=32, 4 waves (2x2), 64x64/wave, 4x4 16x16x32 bf16 MFMA frags.
// A staged bf16 (global_load_lds w=16, XOR-swizzled 16B chunks);
// B staged fp32 (global_load_lds w=16 = 4 floats) and converted to bf16
// during fragment assembly (RNE, same numerics as pre-converted weights).
// Double-buffered, single barrier per K-iter. LDS = 16 + 32 = 48 KB.
// ===========================================================================
struct GemmCore {
    const ushort_t* A; const float* W;
    int m0, n0, tid, lane, w, wm, wn, l15, l4;
    ushort_t (*As)[128 * 32];      // [2][]
    float    (*Bsf)[128 * 32];     // [2][]

    __device__ __forceinline__ void stage(int kk, int buf) {
        #pragma unroll
        for (int i = 0; i < 2; ++i) {
            int c  = i * 256 + tid;            // A chunk 0..511
            int r  = c >> 2;
            int cb = (c & 3) ^ (r & 3);
            __builtin_amdgcn_global_load_lds(
                GP(A + (size_t)(m0 + r) * 1024 + kk + cb * 8),
                LP(&As[buf][c * 8]), 16, 0, 0);
        }
        #pragma unroll
        for (int i = 0; i < 4; ++i) {
            int c  = i * 256 + tid;            // B chunk 0..1023 (4 fp32 each)
            int r  = c >> 3;
            int cb = (c & 7) ^ (r & 7);
            __builtin_amdgcn_global_load_lds(
                GP(W + (size_t)(n0 + r) * 1024 + kk + cb * 4),
                LP(&Bsf[buf][c * 4]), 16, 0, 0);
        }
    }

    __device__ __forceinline__ void run(f32x4 (&acc)[4][4]) {
        stage(0, 0);
        for (int it = 0; it < 32; ++it) {
            __syncthreads();               // buf[it&1] staged; prior reads done
            const ushort_t* Ac = As[it & 1];
            const float*    Bc = Bsf[it & 1];
            if (it + 1 < 32) stage((it + 1) * 32, (it + 1) & 1);

            short8 bfr[4];
            #pragma unroll
            for (int ni = 0; ni < 4; ++ni) {
                int row = wn * 64 + ni * 16 + l15;
                f32x4 lo = *(const f32x4*)(&Bc[(row * 8 + ((l4 * 2)     ^ (row & 7))) * 4]);
                f32x4 hi = *(const f32x4*)(&Bc[(row * 8 + ((l4 * 2 + 1) ^ (row & 7))) * 4]);
                bfr[ni] = pack8(lo, hi);
            }
            #pragma unroll
            for (int mi = 0; mi < 4; ++mi) {
                int row = wm * 64 + mi * 16 + l15;
                short8 af = *(const short8*)(Ac + (row * 4 + (l4 ^ (row & 3))) * 8);
                #pragma unroll
                for (int ni = 0; ni < 4; ++ni)
                    acc[mi][ni] = __builtin_amdgcn_mfma_f32_16x16x32_bf16(
                        af, bfr[ni], acc[mi][ni], 0, 0, 0);
            }
        }
    }
};

// ---------------------------------------------------------------------------
// Fused Q/K/V projection: grid (192, 8); blockIdx.x>>6 selects segment.
// seg 0: Qh head-major bf16, scaled by log2e/8 (exp2-domain softmax)
// seg 1: Kh head-major bf16
// seg 2: Vt transposed [b,h,dk,s] bf16
// ---------------------------------------------------------------------------
__global__ __launch_bounds__(256, 3)
void gemm_qkv(const ushort_t* __restrict__ qb, const ushort_t* __restrict__ kb,
              const ushort_t* __restrict__ vb, const float* __restrict__ Wq,
              const float* __restrict__ Wk, const float* __restrict__ Wv,
              ushort_t* __restrict__ Qh, ushort_t* __restrict__ Kh,
              ushort_t* __restrict__ Vt)
{
    __shared__ ushort_t As[2][128 * 32];
    __shared__ float    Bsf[2][128 * 32];

    const int tid  = threadIdx.x;
    const int lane = tid & 63;
    const int w    = tid >> 6;
    const int seg  = blockIdx.x >> 6;
    const int mb   = blockIdx.x & 63;

    GemmCore core;
    core.A   = (seg == 0) ? qb : (seg == 1) ? kb : vb;
    core.W   = (seg == 0) ? Wq : (seg == 1) ? Wk : Wv;
    core.m0  = mb * 128;
    core.n0  = blockIdx.y * 128;
    core.tid = tid; core.lane = lane; core.w = w;
    core.wm  = w >> 1; core.wn = w & 1;
    core.l15 = lane & 15; core.l4 = lane >> 4;
    core.As  = As; core.Bsf = Bsf;

    f32x4 acc[4][4] = {};
    core.run(acc);

    const float scale = (seg == 0) ? QSCALE : 1.0f;
    ushort_t* outHM = (seg == 0) ? Qh : Kh;

    #pragma unroll
    for (int mi = 0; mi < 4; ++mi) {
        int rowb = core.m0 + core.wm * 64 + mi * 16 + core.l4 * 4;
        #pragma unroll
        for (int ni = 0; ni < 4; ++ni) {
            int n = core.n0 + core.wn * 64 + ni * 16 + core.l15;
            int h = n >> 6, dk = n & 63;
            if (seg < 2) {               // head-major [b,h,s,dk]
                #pragma unroll
                for (int r = 0; r < 4; ++r) {
                    int m = rowb + r, b = m >> 11, s = m & 2047;
                    outHM[(((size_t)(b * 16 + h) * 2048 + s) << 6) + dk] =
                        f2bf(acc[mi][ni][r] * scale);
                }
            } else {                     // V transposed [b,h,dk,s]
                int b = rowb >> 11, s0v = rowb & 2047;
                u16x4 hh;
                #pragma unroll
                for (int r = 0; r < 4; ++r) hh[r] = f2bf(acc[mi][ni][r]);
                *(u16x4*)(Vt + (((size_t)(b * 16 + h) << 6) + dk) * 2048 + s0v) = hh;
            }
        }
    }
}

// ---------------------------------------------------------------------------
// Final projection: out[M,N] fp32 = Ctx bf16 * Wo^T fp32. Grid (64, 8).
// ---------------------------------------------------------------------------
__global__ __launch_bounds__(256, 3)
void gemm_out(const ushort_t* __restrict__ Ctx, const float* __restrict__ Wo,
              float* __restrict__ out)
{
    __shared__ ushort_t As[2][128 * 32];
    __shared__ float    Bsf[2][128 * 32];

    const int tid  = threadIdx.x;
    const int lane = tid & 63;
    const int w    = tid >> 6;

    GemmCore core;
    core.A   = Ctx;  core.W = Wo;
    core.m0  = blockIdx.x * 128;
    core.n0  = blockIdx.y * 128;
    core.tid = tid; core.lane = lane; core.w = w;
    core.wm  = w >> 1; core.wn = w & 1;
    core.l15 = lane & 15; core.l4 = lane >> 4;
    core.As  = As; core.Bsf = Bsf;

    f32x4 acc[4][4] = {};
    core.run(acc);

    #pragma unroll
    for (int mi = 0; mi < 4; ++mi) {
        int rowb = core.m0 + core.wm * 64 + mi * 16 + core.l4 * 4;
        #pragma unroll
        for (int ni = 0; ni < 4; ++ni) {
            int n = core.n0 + core.wn * 64 + ni * 16 + core.l15;
            #pragma unroll
            for (int r = 0; r < 4; ++r)
                out[(size_t)(rowb + r) * 1024 + n] = acc[mi][ni][r];
        }
    }
}

// ---------------------------------------------------------------------------
// Flash-style causal attention (unchanged from R5: 75 µs, absmax-proven).
// S^T orientation, online-max softmax, RNE bf16 P, fp32 row sums, IEEE div.
// Q,K head-major [b,h,s,dk] bf16 (Q pre-scaled); V transposed [b,h,dk,s].
// Double-buffered K/V LDS, one barrier per tile, JIT fragment loads.
// ---------------------------------------------------------------------------
__global__ __launch_bounds__(256, 2)
void attn_fwd5(const ushort_t* __restrict__ Qh, const ushort_t* __restrict__ Kh,
               const ushort_t* __restrict__ Vt, ushort_t* __restrict__ Ctx)
{
    __shared__ ushort_t Kl[2][64 * 64];   // swizzled 16B chunks, double-buffered
    __shared__ ushort_t Vl[2][64 * 64];
    __shared__ ushort_t Pl[4][32][72];    // per-wave P^T [qrow][kcol], +8 pad

    const int tid  = threadIdx.x;
    const int lane = tid & 63;
    const int w    = tid >> 6;
    const int l15  = lane & 15, l4 = lane >> 4;
    const int idx  = blockIdx.x;
    const int qt   = 15 - (idx >> 6);     // heavy q-tiles first
    const int bh   = idx & 63;
    const int b    = bh >> 4, h = bh & 15;
    const int q0   = qt * 128;
    const ushort_t* Qb = Qh + (size_t)bh * SS * DKK;
    const ushort_t* Kb = Kh + (size_t)bh * SS * DKK;
    const ushort_t* Vb = Vt + (size_t)bh * DKK * SS;

    // Q as B-frags: qrow = q0 + w*32 + qg*16 + l15, dk = ks*32 + l4*8 + j
    short8 qf[2][2];
    #pragma unroll
    for (int qg = 0; qg < 2; ++qg)
        #pragma unroll
        for (int ks = 0; ks < 2; ++ks) {
            int row = q0 + w * 32 + qg * 16 + l15;
            qf[qg][ks] = *(const short8*)(Qb + (size_t)row * 64 + ks * 32 + l4 * 8);
        }

    f32x4 Ot[2][4] = {};     // O^T: [qg][nd], col=l15=qrow, row=l4*4+r=dk
    float m_i[2], l_i[2];    // per-row state (row = qg*16+l15), 4 l4-copies in sync
    m_i[0] = m_i[1] = -__builtin_inff();
    l_i[0] = l_i[1] = 0.f;

    auto stage = [&](int k0, ushort_t* Kd, ushort_t* Vd) {
        #pragma unroll
        for (int i = 0; i < 2; ++i) {
            int c  = i * 256 + tid;                    // 0..511
            int r  = c >> 3;
            int cb = (c & 7) ^ (r & 7);
            __builtin_amdgcn_global_load_lds(
                GP(Kb + (size_t)(k0 + r) * 64 + cb * 8), LP(Kd + c * 8), 16, 0, 0);
            __builtin_amdgcn_global_load_lds(
                GP(Vb + (size_t)r * 2048 + k0 + cb * 8), LP(Vd + c * 8), 16, 0, 0);
        }
    };

    const int nkt = 2 * qt + 2;
    const int wrow0 = q0 + w * 32;        // this wave's first q-row
    stage(0, Kl[0], Vl[0]);

    for (int kt = 0; kt < nkt; ++kt) {
        const int k0 = kt * 64;
        __syncthreads();                   // buf[kt&1] staged; prev prefetch drained
        const ushort_t* Kc = Kl[kt & 1];
        const ushort_t* Vc = Vl[kt & 1];
        if (kt + 1 < nkt)                  // prefetch under this tile's compute
            stage(k0 + 64, Kl[(kt + 1) & 1], Vl[(kt + 1) & 1]);

        // ---- Sc^T = K * Q^T : [kcol][qrow]; kf loaded just-in-time ----
        f32x4 sc[2][4] = {};               // [qg][ni]: kcol=ni*16+l4*4+r, qrow=qg*16+l15
        #pragma unroll
        for (int ni = 0; ni < 4; ++ni) {
            short8 kf0, kf1;
            {
                int r = ni * 16 + l15;
                kf0 = *(const short8*)(Kc + (r * 8 + ((0 + l4) ^ (r & 7))) * 8);
                kf1 = *(const short8*)(Kc + (r * 8 + ((4 + l4) ^ (r & 7))) * 8);
            }
            #pragma unroll
            for (int qg = 0; qg < 2; ++qg) {
                sc[qg][ni] = __builtin_amdgcn_mfma_f32_16x16x32_bf16(
                    kf0, qf[qg][0], sc[qg][ni], 0, 0, 0);
                sc[qg][ni] = __builtin_amdgcn_mfma_f32_16x16x32_bf16(
                    kf1, qf[qg][1], sc[qg][ni], 0, 0, 0);
            }
        }

        // ---- causal mask (only near-diagonal tiles) ----
        if (k0 + 63 > wrow0) {
            #pragma unroll
            for (int qg = 0; qg < 2; ++qg) {
                int qrow = wrow0 + qg * 16 + l15;
                #pragma unroll
                for (int ni = 0; ni < 4; ++ni)
                    #pragma unroll
                    for (int r = 0; r < 4; ++r) {
                        int kcol = k0 + ni * 16 + l4 * 4 + r;
                        if (kcol > qrow) sc[qg][ni][r] = -1.0e30f;
                    }
            }
        }

        // ---- online softmax: row = (qg,l15); 16 in-lane + 2 shuffles ----
        #pragma unroll
        for (int qg = 0; qg < 2; ++qg) {
            float mx = sc[qg][0][0];
            #pragma unroll
            for (int ni = 0; ni < 4; ++ni)
                #pragma unroll
                for (int r = 0; r < 4; ++r) mx = fmaxf(mx, sc[qg][ni][r]);
            mx = fmaxf(mx, __shfl_xor(mx, 16, 64));
            mx = fmaxf(mx, __shfl_xor(mx, 32, 64));
            float mnew  = fmaxf(m_i[qg], mx);
            float alpha = EXP2(m_i[qg] - mnew);   // -inf - finite -> 0, no NaN
            float rs = 0.f;
            #pragma unroll
            for (int ni = 0; ni < 4; ++ni)
                #pragma unroll
                for (int r = 0; r < 4; ++r) {
                    float p = EXP2(sc[qg][ni][r] - mnew);
                    sc[qg][ni][r] = p;
                    rs += p;
                }
            rs += __shfl_xor(rs, 16, 64);
            rs += __shfl_xor(rs, 32, 64);
            l_i[qg] = l_i[qg] * alpha + rs;       // fp32 pre-quantization sum
            m_i[qg] = mnew;
            #pragma unroll
            for (int nd = 0; nd < 4; ++nd)
                #pragma unroll
                for (int r = 0; r < 4; ++r) Ot[qg][nd][r] *= alpha;
        }

        // ---- P^T -> per-wave LDS, RNE bf16, packed b64 writes ----
        #pragma unroll
        for (int qg = 0; qg < 2; ++qg) {
            int qr = qg * 16 + l15;
            #pragma unroll
            for (int ni = 0; ni < 4; ++ni) {
                u16x4 hh;
                #pragma unroll
                for (int r = 0; r < 4; ++r) hh[r] = f2bf(sc[qg][ni][r]);
                *(u16x4*)(&Pl[w][qr][ni * 16 + l4 * 4]) = hh;
            }
        }

        // ---- read back as B-frags: P^T[k=kcol][n=qrow] ----
        short8 pT[2][2];
        #pragma unroll
        for (int qg = 0; qg < 2; ++qg)
            #pragma unroll
            for (int ks = 0; ks < 2; ++ks)
                pT[qg][ks] = *(const short8*)(&Pl[w][qg * 16 + l15][ks * 32 + l4 * 8]);

        // ---- O^T += V^T * P^T ; vf loaded just-in-time ----
        #pragma unroll
        for (int nd = 0; nd < 4; ++nd) {
            short8 vf0, vf1;
            {
                int r = nd * 16 + l15;
                vf0 = *(const short8*)(Vc + (r * 8 + ((0 + l4) ^ (r & 7))) * 8);
                vf1 = *(const short8*)(Vc + (r * 8 + ((4 + l4) ^ (r & 7))) * 8);
            }
            #pragma unroll
            for (int qg = 0; qg < 2; ++qg) {
                Ot[qg][nd] = __builtin_amdgcn_mfma_f32_16x16x32_bf16(
                    vf0, pT[qg][0], Ot[qg][nd], 0, 0, 0);
                Ot[qg][nd] = __builtin_amdgcn_mfma_f32_16x16x32_bf16(
                    vf1, pT[qg][1], Ot[qg][nd], 0, 0, 0);
            }
        }
    }

    // ---- epilogue: Ctx[b, qrow, h*64+dk] = O^T / l, packed u16x4 ----
    #pragma unroll
    for (int qg = 0; qg < 2; ++qg) {
        float inv = 1.0f / l_i[qg];           // IEEE divide
        int qrow = q0 + w * 32 + qg * 16 + l15;
        ushort_t* dst = Ctx + ((size_t)b * 2048 + qrow) * 1024 + h * 64;
        #pragma unroll
        for (int nd = 0; nd < 4; ++nd) {
            u16x4 hh;
            #pragma unroll
            for (int r = 0; r < 4; ++r) hh[r] = f2bf(Ot[qg][nd][r] * inv);
            *(u16x4*)(dst + nd * 16 + l4 * 4) = hh;
        }
    }
}

// ---------------------------------------------------------------------------
extern "C" void kernel_launch(void* const* d_in, const int* in_sizes, int n_in,
                              void* d_out, int out_size, void* d_ws, size_t ws_size,
                              hipStream_t stream)
{
    const float* q  = (const float*)d_in[0];
    const float* k  = (const float*)d_in[1];
    const float* v  = (const float*)d_in[2];
    const float* Wq = (const float*)d_in[3];
    const float* Wk = (const float*)d_in[4];
    const float* Wv = (const float*)d_in[5];
    const float* Wo = (const float*)d_in[6];
    float* out = (float*)d_out;

    // ws (67.1 MB, proven): [qb | kb | vb | Vt]; Ctx reuses qb after proj.
    // d_out doubles as bf16 scratch for Qh+Kh (2 x 16.78 MB = exactly 33.55 MB);
    // attn consumes them before gemm_out overwrites d_out with the fp32 result.
    ushort_t* qb  = (ushort_t*)d_ws;
    ushort_t* kb  = qb + (size_t)QKV_N;
    ushort_t* vb  = kb + (size_t)QKV_N;
    ushort_t* Vt  = vb + (size_t)QKV_N;        // [b,h,dk,s]
    ushort_t* Ctx = qb;                        // reuse (dead after gemm_qkv)
    ushort_t* Qh  = (ushort_t*)d_out;          // [b,h,s,dk], pre-scaled
    ushort_t* Kh  = Qh + (size_t)QKV_N;

    cvt3<<<3 * QKV_N / 1024, 256, 0, stream>>>(q, k, v, qb, kb, vb);
    gemm_qkv<<<dim3(192, 8), 256, 0, stream>>>(qb, kb, vb, Wq, Wk, Wv, Qh, Kh, Vt);
    attn_fwd5<<<1024, 256, 0, stream>>>(Qh, Kh, Vt, Ctx);
    gemm_out<<<dim3(64, 8), 256, 0, stream>>>(Ctx, Wo, out);
}

// Round 8
// 327.812 us; speedup vs baseline: 1.1382x; 1.1382x over previous
//
#include <hip/hip_runtime.h>

// Problem constants: B=4, S=2048, D=1024, H=16, DK=64
#define BB 4
#define SS 2048
#define DD 1024
#define HH 16
#define DKK 64
#define MTOT (BB * SS)          // 8192
#define QKV_N (MTOT * DD)       // 8388608 = 2^23
#define W_N (DD * DD)           // 1048576 = 2^20

typedef __attribute__((ext_vector_type(8))) short short8;     // 8 bf16 (MFMA A/B frag)
typedef __attribute__((ext_vector_type(4))) float f32x4;      // MFMA C/D frag
typedef __attribute__((ext_vector_type(4))) unsigned short u16x4;
typedef unsigned short ushort_t;

#define GP(p) ((__attribute__((address_space(1))) void*)(p))
#define LP(p) ((__attribute__((address_space(3))) void*)(p))

// exp2-domain softmax: Q pre-scaled by log2(e)/8 so p = 2^(s-m) via v_exp_f32
#if __has_builtin(__builtin_amdgcn_exp2f)
#define EXP2(x) __builtin_amdgcn_exp2f(x)
#else
#define EXP2(x) __expf((x) * 0.6931471805599453f)
#endif
#define QSCALE 0.1803368801111204f   // (1/8) * log2(e)

__device__ __forceinline__ ushort_t f2bf(float f) {
    union { float f; unsigned u; } c; c.f = f;
    unsigned r = c.u + 0x7fffu + ((c.u >> 16) & 1u);   // RNE; inputs finite
    return (ushort_t)(r >> 16);
}

__device__ __forceinline__ short8 pack8(f32x4 lo, f32x4 hi) {
    short8 r;
    r[0] = (short)f2bf(lo[0]); r[1] = (short)f2bf(lo[1]);
    r[2] = (short)f2bf(lo[2]); r[3] = (short)f2bf(lo[3]);
    r[4] = (short)f2bf(hi[0]); r[5] = (short)f2bf(hi[1]);
    r[6] = (short)f2bf(hi[2]); r[7] = (short)f2bf(hi[3]);
    return r;
}

// ---------------------------------------------------------------------------
// fp32 -> bf16 convert of the 4 weight matrices (4 x 2^20) into ws
// ---------------------------------------------------------------------------
__global__ __launch_bounds__(256)
void cvtW(const float* __restrict__ Wq, const float* __restrict__ Wk,
          const float* __restrict__ Wv, const float* __restrict__ Wo,
          ushort_t* __restrict__ dst)
{
    int i = (blockIdx.x * 256 + threadIdx.x) * 4;
    int seg = i >> 20;
    int off = i & (W_N - 1);
    const float* s = (seg == 0) ? Wq : (seg == 1) ? Wk : (seg == 2) ? Wv : Wo;
    f32x4 x = *(const f32x4*)(s + off);
    u16x4 h;
    h[0] = f2bf(x[0]); h[1] = f2bf(x[1]); h[2] = f2bf(x[2]); h[3] = f2bf(x[3]);
    *(u16x4*)(dst + i) = h;
}

// ---------------------------------------------------------------------------
// Fused Q/K/V projection: grid (192, 8); blockIdx.x>>6 selects segment.
// A = ORIGINAL fp32 q/k/v, staged fp32 via global_load_lds (no cvt pass),
// converted to bf16 during fragment assembly. B = pre-converted bf16 weights.
// 128x128 tile, BK=32, double-buffered, one barrier/iter. LDS 32+16=48 KB.
// seg 0: Qh head-major bf16 scaled log2e/8; seg 1: Kh; seg 2: Vt [b,h,dk,s].
// ---------------------------------------------------------------------------
__global__ __launch_bounds__(256, 3)
void gemm_qkv(const float* __restrict__ q, const float* __restrict__ k,
              const float* __restrict__ v, const ushort_t* __restrict__ wb,
              ushort_t* __restrict__ Qh, ushort_t* __restrict__ Kh,
              ushort_t* __restrict__ Vt)
{
    __shared__ float    Asf[2][128 * 32];
    __shared__ ushort_t Bs [2][128 * 32];

    const int tid  = threadIdx.x;
    const int lane = tid & 63;
    const int w    = tid >> 6;
    const int wm   = w >> 1, wn = w & 1;
    const int l15  = lane & 15, l4 = lane >> 4;
    const int seg  = blockIdx.x >> 6;
    const int m0   = (blockIdx.x & 63) * 128;
    const int n0   = blockIdx.y * 128;
    const float* A = (seg == 0) ? q : (seg == 1) ? k : v;
    const ushort_t* W = wb + (size_t)seg * W_N;

    auto stage = [&](int kk, int buf) {
        #pragma unroll
        for (int i = 0; i < 4; ++i) {          // A fp32: 1024 x 16B chunks
            int c = i * 256 + tid, r = c >> 3, cb = (c & 7) ^ (r & 7);
            __builtin_amdgcn_global_load_lds(
                GP(A + (size_t)(m0 + r) * 1024 + kk + cb * 4),
                LP(&Asf[buf][c * 4]), 16, 0, 0);
        }
        #pragma unroll
        for (int i = 0; i < 2; ++i) {          // B bf16: 512 x 16B chunks
            int c = i * 256 + tid, r = c >> 2, cb = (c & 3) ^ ((r >> 1) & 3);
            __builtin_amdgcn_global_load_lds(
                GP(W + (size_t)(n0 + r) * 1024 + kk + cb * 8),
                LP(&Bs[buf][c * 8]), 16, 0, 0);
        }
    };

    f32x4 acc[4][4] = {};
    stage(0, 0);

    for (int it = 0; it < 32; ++it) {
        __syncthreads();                       // buf[it&1] staged; prior reads done
        const float*    Ac = Asf[it & 1];
        const ushort_t* Bc = Bs[it & 1];
        if (it + 1 < 32) stage((it + 1) * 32, (it + 1) & 1);

        short8 bfr[4];
        #pragma unroll
        for (int ni = 0; ni < 4; ++ni) {
            int row = wn * 64 + ni * 16 + l15;
            bfr[ni] = *(const short8*)(Bc + (row * 4 + (l4 ^ ((row >> 1) & 3))) * 8);
        }
        #pragma unroll
        for (int mi = 0; mi < 4; ++mi) {
            int row = wm * 64 + mi * 16 + l15;
            f32x4 lo = *(const f32x4*)(&Ac[(row * 8 + ((l4 * 2)     ^ (row & 7))) * 4]);
            f32x4 hi = *(const f32x4*)(&Ac[(row * 8 + ((l4 * 2 + 1) ^ (row & 7))) * 4]);
            short8 af = pack8(lo, hi);
            #pragma unroll
            for (int ni = 0; ni < 4; ++ni)
                acc[mi][ni] = __builtin_amdgcn_mfma_f32_16x16x32_bf16(
                    af, bfr[ni], acc[mi][ni], 0, 0, 0);
        }
    }

    const float scale = (seg == 0) ? QSCALE : 1.0f;
    ushort_t* outHM = (seg == 0) ? Qh : Kh;

    #pragma unroll
    for (int mi = 0; mi < 4; ++mi) {
        int rowb = m0 + wm * 64 + mi * 16 + l4 * 4;
        #pragma unroll
        for (int ni = 0; ni < 4; ++ni) {
            int n = n0 + wn * 64 + ni * 16 + l15;
            int h = n >> 6, dk = n & 63;
            if (seg < 2) {               // head-major [b,h,s,dk]
                #pragma unroll
                for (int r = 0; r < 4; ++r) {
                    int m = rowb + r, b = m >> 11, s = m & 2047;
                    outHM[(((size_t)(b * 16 + h) * 2048 + s) << 6) + dk] =
                        f2bf(acc[mi][ni][r] * scale);
                }
            } else {                     // V transposed [b,h,dk,s]
                int b = rowb >> 11, s0v = rowb & 2047;
                u16x4 hh;
                #pragma unroll
                for (int r = 0; r < 4; ++r) hh[r] = f2bf(acc[mi][ni][r]);
                *(u16x4*)(Vt + (((size_t)(b * 16 + h) << 6) + dk) * 2048 + s0v) = hh;
            }
        }
    }
}

// ---------------------------------------------------------------------------
// Final projection: out[M,1024] fp32 = Ctx bf16 * Wo^T bf16.
// 128x64 tiles -> grid (64,16) = 1024 blocks = 4 blocks/CU (grid depth was
// the R6/R7-proven limiter at 512 blocks). 4 waves (2x2), 64x32 per wave,
// 4x2 frags. LDS 2x8 + 2x4 = 24 KB, double-buffered, one barrier/iter.
// ---------------------------------------------------------------------------
__global__ __launch_bounds__(256, 4)
void gemm_out(const ushort_t* __restrict__ Ctx, const ushort_t* __restrict__ wo,
              float* __restrict__ out)
{
    __shared__ ushort_t As[2][128 * 32];
    __shared__ ushort_t Bs[2][64 * 32];

    const int tid  = threadIdx.x;
    const int lane = tid & 63;
    const int w    = tid >> 6;
    const int wm   = w >> 1, wn = w & 1;
    const int l15  = lane & 15, l4 = lane >> 4;
    const int m0   = blockIdx.x * 128;
    const int n0   = blockIdx.y * 64;

    auto stage = [&](int kk, int buf) {
        #pragma unroll
        for (int i = 0; i < 2; ++i) {          // A bf16: 512 chunks
            int c = i * 256 + tid, r = c >> 2, cb = (c & 3) ^ ((r >> 1) & 3);
            __builtin_amdgcn_global_load_lds(
                GP(Ctx + (size_t)(m0 + r) * 1024 + kk + cb * 8),
                LP(&As[buf][c * 8]), 16, 0, 0);
        }
        {                                      // B bf16: 256 chunks
            int c = tid, r = c >> 2, cb = (c & 3) ^ ((r >> 1) & 3);
            __builtin_amdgcn_global_load_lds(
                GP(wo + (size_t)(n0 + r) * 1024 + kk + cb * 8),
                LP(&Bs[buf][c * 8]), 16, 0, 0);
        }
    };

    f32x4 acc[4][2] = {};
    stage(0, 0);

    for (int it = 0; it < 32; ++it) {
        __syncthreads();
        const ushort_t* Ac = As[it & 1];
        const ushort_t* Bc = Bs[it & 1];
        if (it + 1 < 32) stage((it + 1) * 32, (it + 1) & 1);

        short8 bfr[2];
        #pragma unroll
        for (int ni = 0; ni < 2; ++ni) {
            int row = wn * 32 + ni * 16 + l15;
            bfr[ni] = *(const short8*)(Bc + (row * 4 + (l4 ^ ((row >> 1) & 3))) * 8);
        }
        #pragma unroll
        for (int mi = 0; mi < 4; ++mi) {
            int row = wm * 64 + mi * 16 + l15;
            short8 af = *(const short8*)(Ac + (row * 4 + (l4 ^ ((row >> 1) & 3))) * 8);
            #pragma unroll
            for (int ni = 0; ni < 2; ++ni)
                acc[mi][ni] = __builtin_amdgcn_mfma_f32_16x16x32_bf16(
                    af, bfr[ni], acc[mi][ni], 0, 0, 0);
        }
    }

    #pragma unroll
    for (int mi = 0; mi < 4; ++mi) {
        int rowb = m0 + wm * 64 + mi * 16 + l4 * 4;
        #pragma unroll
        for (int ni = 0; ni < 2; ++ni) {
            int n = n0 + wn * 32 + ni * 16 + l15;
            #pragma unroll
            for (int r = 0; r < 4; ++r)
                out[(size_t)(rowb + r) * 1024 + n] = acc[mi][ni][r];
        }
    }
}

// ---------------------------------------------------------------------------
// Flash-style causal attention (R5 structure, 75 µs proven; now 3 blocks/CU:
// LDS 51.2 KB x 3 = 153.6 KB fits, VGPR 76 << 170 cap -> no spill risk).
// S^T orientation, online-max softmax, RNE bf16 P, fp32 row sums, IEEE div.
// ---------------------------------------------------------------------------
__global__ __launch_bounds__(256, 3)
void attn_fwd5(const ushort_t* __restrict__ Qh, const ushort_t* __restrict__ Kh,
               const ushort_t* __restrict__ Vt, ushort_t* __restrict__ Ctx)
{
    __shared__ ushort_t Kl[2][64 * 64];   // swizzled 16B chunks, double-buffered
    __shared__ ushort_t Vl[2][64 * 64];
    __shared__ ushort_t Pl[4][32][72];    // per-wave P^T [qrow][kcol], +8 pad

    const int tid  = threadIdx.x;
    const int lane = tid & 63;
    const int w    = tid >> 6;
    const int l15  = lane & 15, l4 = lane >> 4;
    const int idx  = blockIdx.x;
    const int qt   = 15 - (idx >> 6);     // heavy q-tiles first
    const int bh   = idx & 63;
    const int b    = bh >> 4, h = bh & 15;
    const int q0   = qt * 128;
    const ushort_t* Qb = Qh + (size_t)bh * SS * DKK;
    const ushort_t* Kb = Kh + (size_t)bh * SS * DKK;
    const ushort_t* Vb = Vt + (size_t)bh * DKK * SS;

    // Q as B-frags: qrow = q0 + w*32 + qg*16 + l15, dk = ks*32 + l4*8 + j
    short8 qf[2][2];
    #pragma unroll
    for (int qg = 0; qg < 2; ++qg)
        #pragma unroll
        for (int ks = 0; ks < 2; ++ks) {
            int row = q0 + w * 32 + qg * 16 + l15;
            qf[qg][ks] = *(const short8*)(Qb + (size_t)row * 64 + ks * 32 + l4 * 8);
        }

    f32x4 Ot[2][4] = {};     // O^T: [qg][nd], col=l15=qrow, row=l4*4+r=dk
    float m_i[2], l_i[2];
    m_i[0] = m_i[1] = -__builtin_inff();
    l_i[0] = l_i[1] = 0.f;

    auto stage = [&](int k0, ushort_t* Kd, ushort_t* Vd) {
        #pragma unroll
        for (int i = 0; i < 2; ++i) {
            int c  = i * 256 + tid;                    // 0..511
            int r  = c >> 3;
            int cb = (c & 7) ^ (r & 7);
            __builtin_amdgcn_global_load_lds(
                GP(Kb + (size_t)(k0 + r) * 64 + cb * 8), LP(Kd + c * 8), 16, 0, 0);
            __builtin_amdgcn_global_load_lds(
                GP(Vb + (size_t)r * 2048 + k0 + cb * 8), LP(Vd + c * 8), 16, 0, 0);
        }
    };

    const int nkt = 2 * qt + 2;
    const int wrow0 = q0 + w * 32;
    stage(0, Kl[0], Vl[0]);

    for (int kt = 0; kt < nkt; ++kt) {
        const int k0 = kt * 64;
        __syncthreads();                   // buf[kt&1] staged; prev prefetch drained
        const ushort_t* Kc = Kl[kt & 1];
        const ushort_t* Vc = Vl[kt & 1];
        if (kt + 1 < nkt)
            stage(k0 + 64, Kl[(kt + 1) & 1], Vl[(kt + 1) & 1]);

        // ---- Sc^T = K * Q^T : [kcol][qrow]; kf loaded just-in-time ----
        f32x4 sc[2][4] = {};
        #pragma unroll
        for (int ni = 0; ni < 4; ++ni) {
            short8 kf0, kf1;
            {
                int r = ni * 16 + l15;
                kf0 = *(const short8*)(Kc + (r * 8 + ((0 + l4) ^ (r & 7))) * 8);
                kf1 = *(const short8*)(Kc + (r * 8 + ((4 + l4) ^ (r & 7))) * 8);
            }
            #pragma unroll
            for (int qg = 0; qg < 2; ++qg) {
                sc[qg][ni] = __builtin_amdgcn_mfma_f32_16x16x32_bf16(
                    kf0, qf[qg][0], sc[qg][ni], 0, 0, 0);
                sc[qg][ni] = __builtin_amdgcn_mfma_f32_16x16x32_bf16(
                    kf1, qf[qg][1], sc[qg][ni], 0, 0, 0);
            }
        }

        // ---- causal mask (only near-diagonal tiles) ----
        if (k0 + 63 > wrow0) {
            #pragma unroll
            for (int qg = 0; qg < 2; ++qg) {
                int qrow = wrow0 + qg * 16 + l15;
                #pragma unroll
                for (int ni = 0; ni < 4; ++ni)
                    #pragma unroll
                    for (int r = 0; r < 4; ++r) {
                        int kcol = k0 + ni * 16 + l4 * 4 + r;
                        if (kcol > qrow) sc[qg][ni][r] = -1.0e30f;
                    }
            }
        }

        // ---- online softmax: row = (qg,l15); 16 in-lane + 2 shuffles ----
        #pragma unroll
        for (int qg = 0; qg < 2; ++qg) {
            float mx = sc[qg][0][0];
            #pragma unroll
            for (int ni = 0; ni < 4; ++ni)
                #pragma unroll
                for (int r = 0; r < 4; ++r) mx = fmaxf(mx, sc[qg][ni][r]);
            mx = fmaxf(mx, __shfl_xor(mx, 16, 64));
            mx = fmaxf(mx, __shfl_xor(mx, 32, 64));
            float mnew  = fmaxf(m_i[qg], mx);
            float alpha = EXP2(m_i[qg] - mnew);
            float rs = 0.f;
            #pragma unroll
            for (int ni = 0; ni < 4; ++ni)
                #pragma unroll
                for (int r = 0; r < 4; ++r) {
                    float p = EXP2(sc[qg][ni][r] - mnew);
                    sc[qg][ni][r] = p;
                    rs += p;
                }
            rs += __shfl_xor(rs, 16, 64);
            rs += __shfl_xor(rs, 32, 64);
            l_i[qg] = l_i[qg] * alpha + rs;
            m_i[qg] = mnew;
            #pragma unroll
            for (int nd = 0; nd < 4; ++nd)
                #pragma unroll
                for (int r = 0; r < 4; ++r) Ot[qg][nd][r] *= alpha;
        }

        // ---- P^T -> per-wave LDS, RNE bf16, packed b64 writes ----
        #pragma unroll
        for (int qg = 0; qg < 2; ++qg) {
            int qr = qg * 16 + l15;
            #pragma unroll
            for (int ni = 0; ni < 4; ++ni) {
                u16x4 hh;
                #pragma unroll
                for (int r = 0; r < 4; ++r) hh[r] = f2bf(sc[qg][ni][r]);
                *(u16x4*)(&Pl[w][qr][ni * 16 + l4 * 4]) = hh;
            }
        }

        // ---- read back as B-frags: P^T[k=kcol][n=qrow] ----
        short8 pT[2][2];
        #pragma unroll
        for (int qg = 0; qg < 2; ++qg)
            #pragma unroll
            for (int ks = 0; ks < 2; ++ks)
                pT[qg][ks] = *(const short8*)(&Pl[w][qg * 16 + l15][ks * 32 + l4 * 8]);

        // ---- O^T += V^T * P^T ; vf loaded just-in-time ----
        #pragma unroll
        for (int nd = 0; nd < 4; ++nd) {
            short8 vf0, vf1;
            {
                int r = nd * 16 + l15;
                vf0 = *(const short8*)(Vc + (r * 8 + ((0 + l4) ^ (r & 7))) * 8);
                vf1 = *(const short8*)(Vc + (r * 8 + ((4 + l4) ^ (r & 7))) * 8);
            }
            #pragma unroll
            for (int qg = 0; qg < 2; ++qg) {
                Ot[qg][nd] = __builtin_amdgcn_mfma_f32_16x16x32_bf16(
                    vf0, pT[qg][0], Ot[qg][nd], 0, 0, 0);
                Ot[qg][nd] = __builtin_amdgcn_mfma_f32_16x16x32_bf16(
                    vf1, pT[qg][1], Ot[qg][nd], 0, 0, 0);
            }
        }
    }

    // ---- epilogue: Ctx[b, qrow, h*64+dk] = O^T / l, packed u16x4 ----
    #pragma unroll
    for (int qg = 0; qg < 2; ++qg) {
        float inv = 1.0f / l_i[qg];
        int qrow = q0 + w * 32 + qg * 16 + l15;
        ushort_t* dst = Ctx + ((size_t)b * 2048 + qrow) * 1024 + h * 64;
        #pragma unroll
        for (int nd = 0; nd < 4; ++nd) {
            u16x4 hh;
            #pragma unroll
            for (int r = 0; r < 4; ++r) hh[r] = f2bf(Ot[qg][nd][r] * inv);
            *(u16x4*)(dst + nd * 16 + l4 * 4) = hh;
        }
    }
}

// ---------------------------------------------------------------------------
extern "C" void kernel_launch(void* const* d_in, const int* in_sizes, int n_in,
                              void* d_out, int out_size, void* d_ws, size_t ws_size,
                              hipStream_t stream)
{
    const float* q  = (const float*)d_in[0];
    const float* k  = (const float*)d_in[1];
    const float* v  = (const float*)d_in[2];
    const float* Wq = (const float*)d_in[3];
    const float* Wk = (const float*)d_in[4];
    const float* Wv = (const float*)d_in[5];
    const float* Wo = (const float*)d_in[6];
    float* out = (float*)d_out;

    // ws (41.9 MB used, well under the proven 67.1):
    //   [wq|wk|wv|wo bf16 (8 MB) | Vt (16.78 MB) | Ctx (16.78 MB)]
    // d_out doubles as Qh+Kh bf16 scratch (exactly 33.55 MB); attn consumes
    // them before gemm_out overwrites d_out with the fp32 result.
    ushort_t* wb  = (ushort_t*)d_ws;           // [4][W_N]: wq,wk,wv,wo
    ushort_t* Vt  = wb + (size_t)4 * W_N;      // [b,h,dk,s]
    ushort_t* Ctx = Vt + (size_t)QKV_N;
    ushort_t* Qh  = (ushort_t*)d_out;          // [b,h,s,dk], pre-scaled
    ushort_t* Kh  = Qh + (size_t)QKV_N;

    cvtW<<<4 * W_N / 1024, 256, 0, stream>>>(Wq, Wk, Wv, Wo, wb);
    gemm_qkv<<<dim3(192, 8), 256, 0, stream>>>(q, k, v, wb, Qh, Kh, Vt);
    attn_fwd5<<<1024, 256, 0, stream>>>(Qh, Kh, Vt, Ctx);
    gemm_out<<<dim3(64, 16), 256, 0, stream>>>(Ctx, wb + (size_t)3 * W_N, out);
}